// Round 5
// baseline (1194.875 us; speedup 1.0000x reference)
//
#include <hip/hip_runtime.h>
#include <hip/hip_bf16.h>
#include <hip/hip_cooperative_groups.h>
#include <math.h>

namespace cg = cooperative_groups;

#define TM1 16
#define TT 17

typedef __attribute__((ext_vector_type(8))) __bf16 bf16x8;
typedef __attribute__((ext_vector_type(4))) float f32x4;

// ---------------- workspace layout (float units, all 16B-aligned) ----------------
#define OFF_STATS  0          // 32 f
#define OFF_BSTATS 32         // 512*32 f
#define OFF_H0     16416      // 512*512 f
#define OFF_H1     278560     // 512*512 f
#define OFF_HB0    540704     // 512*512 bf16 (131072 f-units)
#define OFF_HB1    671776
#define OFF_SPB    802848     // 512*256 bf16 (65536 f-units)
#define OFF_PWB    868384     // 256*512 bf16 (65536 f-units)

// prep: pw -> bf16, zero h0/hb0
__global__ void prep_k(const float* __restrict__ pw, __hip_bfloat16* __restrict__ pwb,
                       float* __restrict__ h0, float* __restrict__ hb0f) {
  int i = blockIdx.x * blockDim.x + threadIdx.x;
  int st = gridDim.x * blockDim.x;
  for (int j = i; j < 256 * 512; j += st) pwb[j] = __float2bfloat16(pw[j]);
  for (int j = i; j < 512 * 512; j += st) h0[j] = 0.0f;
  for (int j = i; j < 512 * 512 / 2; j += st) hb0f[j] = 0.0f;
}

// ---------------- Encoder pass A: conv + per-block channel sum/sumsq ----------------
__global__ __launch_bounds__(256) void enc_conv_stats(const float* __restrict__ x,
                                                      const float* __restrict__ cw,
                                                      float* __restrict__ bstats) {
  __shared__ float imgp[2 * 66 * 66];
  __shared__ float reds[4][16], redq[4][16];
  const int b = blockIdx.x, tid = threadIdx.x;
  const int wv = tid >> 6;
  for (int i = tid; i < 2 * 66 * 66; i += 256) imgp[i] = 0.0f;
  __syncthreads();
  const float* xb = x + b * 8192;
  for (int i = tid; i < 8192; i += 256) {
    int ci = i >> 12, rem = i & 4095, y = rem >> 6, xx = rem & 63;
    imgp[ci * 4356 + (y + 1) * 66 + (xx + 1)] = xb[i];
  }
  __syncthreads();

  for (int c4 = 0; c4 < 4; ++c4) {
    float w0[18], w1[18], w2[18], w3[18];
#pragma unroll
    for (int k = 0; k < 18; ++k) {
      w0[k] = cw[(c4 * 4 + 0) * 18 + k];
      w1[k] = cw[(c4 * 4 + 1) * 18 + k];
      w2[k] = cw[(c4 * 4 + 2) * 18 + k];
      w3[k] = cw[(c4 * 4 + 3) * 18 + k];
    }
    float s0 = 0, s1 = 0, s2 = 0, s3 = 0, q0 = 0, q1 = 0, q2 = 0, q3 = 0;
    for (int p = tid; p < 4096; p += 256) {
      int y = p >> 6, xx = p & 63;
      float v[18];
#pragma unroll
      for (int ci = 0; ci < 2; ++ci)
#pragma unroll
        for (int dy = 0; dy < 3; ++dy)
#pragma unroll
          for (int dx = 0; dx < 3; ++dx)
            v[ci * 9 + dy * 3 + dx] = imgp[ci * 4356 + (y + dy) * 66 + (xx + dx)];
      float a0 = 0, a1 = 0, a2 = 0, a3 = 0;
#pragma unroll
      for (int k = 0; k < 18; ++k) {
        a0 = fmaf(w0[k], v[k], a0);
        a1 = fmaf(w1[k], v[k], a1);
        a2 = fmaf(w2[k], v[k], a2);
        a3 = fmaf(w3[k], v[k], a3);
      }
      s0 += a0; q0 = fmaf(a0, a0, q0);
      s1 += a1; q1 = fmaf(a1, a1, q1);
      s2 += a2; q2 = fmaf(a2, a2, q2);
      s3 += a3; q3 = fmaf(a3, a3, q3);
    }
#pragma unroll
    for (int off = 32; off >= 1; off >>= 1) {
      s0 += __shfl_down(s0, off); q0 += __shfl_down(q0, off);
      s1 += __shfl_down(s1, off); q1 += __shfl_down(q1, off);
      s2 += __shfl_down(s2, off); q2 += __shfl_down(q2, off);
      s3 += __shfl_down(s3, off); q3 += __shfl_down(q3, off);
    }
    if ((tid & 63) == 0) {
      reds[wv][c4 * 4 + 0] = s0; redq[wv][c4 * 4 + 0] = q0;
      reds[wv][c4 * 4 + 1] = s1; redq[wv][c4 * 4 + 1] = q1;
      reds[wv][c4 * 4 + 2] = s2; redq[wv][c4 * 4 + 2] = q2;
      reds[wv][c4 * 4 + 3] = s3; redq[wv][c4 * 4 + 3] = q3;
    }
  }
  __syncthreads();
  if (tid < 16)
    bstats[b * 32 + tid] = reds[0][tid] + reds[1][tid] + reds[2][tid] + reds[3][tid];
  else if (tid < 32) {
    int c = tid - 16;
    bstats[b * 32 + tid] = redq[0][c] + redq[1][c] + redq[2][c] + redq[3][c];
  }
}

// reduce 512 x 32 partials -> 32 stats (deterministic, no atomics)
__global__ __launch_bounds__(256) void reduce_stats_k(const float* __restrict__ bstats,
                                                      float* __restrict__ stats) {
  __shared__ float acc[8][32];
  const int c = threadIdx.x & 31, part = threadIdx.x >> 5;
  float s = 0;
  for (int b = part; b < 512; b += 8) s += bstats[b * 32 + c];
  acc[part][c] = s;
  __syncthreads();
  if (threadIdx.x < 32) {
    float t = 0;
#pragma unroll
    for (int p = 0; p < 8; ++p) t += acc[p][threadIdx.x];
    stats[threadIdx.x] = t;
  }
}

// ---- Encoder pass B: conv + BN + relu + maxpool + avgpool + FC -> s0 ----
__global__ __launch_bounds__(256) void enc_finish(const float* __restrict__ x,
                                                  const float* __restrict__ cw,
                                                  const float* __restrict__ stats,
                                                  const float* __restrict__ gamma,
                                                  const float* __restrict__ beta,
                                                  const float* __restrict__ fcw,
                                                  const float* __restrict__ fcb,
                                                  __hip_bfloat16* __restrict__ spb,
                                                  float* __restrict__ out) {
  __shared__ float imgp[2 * 66 * 66];
  __shared__ float red[4][16];
  __shared__ float plds[16];
  const int b = blockIdx.x, tid = threadIdx.x;
  for (int i = tid; i < 2 * 66 * 66; i += 256) imgp[i] = 0.0f;
  __syncthreads();
  const float* xb = x + b * 8192;
  for (int i = tid; i < 8192; i += 256) {
    int ci = i >> 12, rem = i & 4095, y = rem >> 6, xx = rem & 63;
    imgp[ci * 4356 + (y + 1) * 66 + (xx + 1)] = xb[i];
  }
  __syncthreads();

  const float invN = 1.0f / (512.0f * 4096.0f);
  const int wv = tid >> 6;

  for (int c4 = 0; c4 < 4; ++c4) {
    float w0[18], w1[18], w2[18], w3[18];
#pragma unroll
    for (int k = 0; k < 18; ++k) {
      w0[k] = cw[(c4 * 4 + 0) * 18 + k];
      w1[k] = cw[(c4 * 4 + 1) * 18 + k];
      w2[k] = cw[(c4 * 4 + 2) * 18 + k];
      w3[k] = cw[(c4 * 4 + 3) * 18 + k];
    }
    float sc0, sc1, sc2, sc3, sh0, sh1, sh2, sh3;
    {
      int c = c4 * 4 + 0; float m = stats[c] * invN; float var = stats[16 + c] * invN - m * m;
      float isd = rsqrtf(var + 1e-5f); sc0 = gamma[c] * isd; sh0 = beta[c] - m * sc0;
      c = c4 * 4 + 1; m = stats[c] * invN; var = stats[16 + c] * invN - m * m;
      isd = rsqrtf(var + 1e-5f); sc1 = gamma[c] * isd; sh1 = beta[c] - m * sc1;
      c = c4 * 4 + 2; m = stats[c] * invN; var = stats[16 + c] * invN - m * m;
      isd = rsqrtf(var + 1e-5f); sc2 = gamma[c] * isd; sh2 = beta[c] - m * sc2;
      c = c4 * 4 + 3; m = stats[c] * invN; var = stats[16 + c] * invN - m * m;
      isd = rsqrtf(var + 1e-5f); sc3 = gamma[c] * isd; sh3 = beta[c] - m * sc3;
    }
    float p0 = 0, p1 = 0, p2 = 0, p3 = 0;
    for (int q = tid; q < 1024; q += 256) {
      int py = q >> 5, px = q & 31;
      float m0 = 0, m1 = 0, m2 = 0, m3 = 0;
#pragma unroll
      for (int sy = 0; sy < 2; ++sy)
#pragma unroll
        for (int sx = 0; sx < 2; ++sx) {
          int y = 2 * py + sy, xx = 2 * px + sx;
          float v[18];
#pragma unroll
          for (int ci = 0; ci < 2; ++ci)
#pragma unroll
            for (int dy = 0; dy < 3; ++dy)
#pragma unroll
              for (int dx = 0; dx < 3; ++dx)
                v[ci * 9 + dy * 3 + dx] = imgp[ci * 4356 + (y + dy) * 66 + (xx + dx)];
          float a0 = 0, a1 = 0, a2 = 0, a3 = 0;
#pragma unroll
          for (int k = 0; k < 18; ++k) {
            a0 = fmaf(w0[k], v[k], a0);
            a1 = fmaf(w1[k], v[k], a1);
            a2 = fmaf(w2[k], v[k], a2);
            a3 = fmaf(w3[k], v[k], a3);
          }
          m0 = fmaxf(m0, fmaxf(fmaf(a0, sc0, sh0), 0.0f));
          m1 = fmaxf(m1, fmaxf(fmaf(a1, sc1, sh1), 0.0f));
          m2 = fmaxf(m2, fmaxf(fmaf(a2, sc2, sh2), 0.0f));
          m3 = fmaxf(m3, fmaxf(fmaf(a3, sc3, sh3), 0.0f));
        }
      p0 += m0; p1 += m1; p2 += m2; p3 += m3;
    }
#pragma unroll
    for (int off = 32; off >= 1; off >>= 1) {
      p0 += __shfl_down(p0, off);
      p1 += __shfl_down(p1, off);
      p2 += __shfl_down(p2, off);
      p3 += __shfl_down(p3, off);
    }
    if ((tid & 63) == 0) {
      red[wv][c4 * 4 + 0] = p0;
      red[wv][c4 * 4 + 1] = p1;
      red[wv][c4 * 4 + 2] = p2;
      red[wv][c4 * 4 + 3] = p3;
    }
  }
  __syncthreads();
  if (tid < 16)
    plds[tid] = (red[0][tid] + red[1][tid] + red[2][tid] + red[3][tid]) * (1.0f / 1024.0f);
  __syncthreads();

  float acc = fcb[tid];
#pragma unroll
  for (int c = 0; c < 16; ++c) acc = fmaf(plds[c], fcw[tid * 16 + c], acc);
  spb[b * 256 + tid] = __float2bfloat16(acc);
  out[(b * TT + 0) * 256 + tid] = acc;
}

// ---------------- Persistent cooperative scan ----------------
// grid = 256 blocks x 256 threads (1 block/CU via 144 KB LDS).
// block b: bx = b&15 (col group), by = b>>4 (row band of 32).
// LDS holds this block's whh slice (3 gates x 32 cols x 512 K) and wih slice
// (3 x 32 x 256), bf16, k-chunk-major [kc][c][8] so B-frag reads are contiguous.
// Per step: [pred t>0: waves 0,1, 16x16 tile, pwb from L2] gridsync [gates] gridsync.
__global__ __launch_bounds__(256) void scan_coop(
    __hip_bfloat16* __restrict__ spb,          // 512x256 s(t) bf16
    float* __restrict__ h0, float* __restrict__ h1,
    __hip_bfloat16* __restrict__ hb0, __hip_bfloat16* __restrict__ hb1,
    const float* __restrict__ wih,             // 1536x258 fp32
    const float* __restrict__ whh,             // 1536x512 fp32
    const __hip_bfloat16* __restrict__ pwb,    // 256x512 bf16
    const float* __restrict__ pb,
    const float* __restrict__ actions,         // 512x16x2
    const float* __restrict__ bih, const float* __restrict__ bhh,
    float* __restrict__ out) {
  extern __shared__ __hip_bfloat16 lds[];
  __hip_bfloat16* whhL = lds;           // 49152 elems
  __hip_bfloat16* wihL = lds + 49152;   // 24576 elems
  cg::grid_group grid = cg::this_grid();

  const int tid = threadIdx.x;
  const int w = tid >> 6, lane = tid & 63;
  const int l15 = lane & 15, hi = lane >> 4;
  const int bx = blockIdx.x & 15, by = blockIdx.x >> 4;
  const int row0 = by * 32;
  const int m = w & 1, tc = w >> 1;

  // ---- one-time: stage weight slices into LDS (fp32 -> bf16, k-chunk-major) ----
  for (int idx = tid; idx < 49152; idx += 256) {
    int g = idx >> 14, rem = idx & 16383;
    int kc = rem >> 8, r2 = rem & 255, c = r2 >> 3, kl = r2 & 7;
    whhL[idx] = __float2bfloat16(whh[(g * 512 + bx * 32 + c) * 512 + kc * 8 + kl]);
  }
  for (int idx = tid; idx < 24576; idx += 256) {
    int g = idx >> 13, rem = idx & 8191;
    int kc = rem >> 8, r2 = rem & 255, c = r2 >> 3, kl = r2 & 7;
    wihL[idx] = __float2bfloat16(wih[(g * 512 + bx * 32 + c) * 258 + kc * 8 + kl]);
  }
  __syncthreads();

  // ---- loop-invariant epilogue constants ----
  const int colg = bx * 32 + tc * 16 + l15;
  const float br = bih[colg] + bhh[colg];
  const float bz = bih[512 + colg] + bhh[512 + colg];
  const float bxn = bih[1024 + colg];
  const float bhn = bhh[1024 + colg];
  const float wur = wih[colg * 258 + 256], wvr = wih[colg * 258 + 257];
  const float wuz = wih[(512 + colg) * 258 + 256], wvz = wih[(512 + colg) * 258 + 257];
  const float wun = wih[(1024 + colg) * 258 + 256], wvn = wih[(1024 + colg) * 258 + 257];
  const int colp = bx * 16 + l15;
  const float pbias = pb[colp];
  const int cloc8 = (tc * 16 + l15) * 8;

  for (int t = 0; t <= 16; ++t) {
    const float* hc = (t & 1) ? h1 : h0;
    const __hip_bfloat16* hbc = (t & 1) ? hb1 : hb0;
    float* hn_ = (t & 1) ? h0 : h1;
    __hip_bfloat16* hbn = (t & 1) ? hb0 : hb1;

    if (t > 0 && w < 2) {
      // pred: s(t) = relu(h(t) @ P^T + pb), rows row0+w*16, cols colp
      f32x4 acc = {0.f, 0.f, 0.f, 0.f};
      const __hip_bfloat16* ap = hbc + (row0 + w * 16 + l15) * 512 + hi * 8;
      const __hip_bfloat16* bp = pwb + colp * 512 + hi * 8;
#pragma unroll
      for (int k0 = 0; k0 < 512; k0 += 32)
        acc = __builtin_amdgcn_mfma_f32_16x16x32_bf16(*(const bf16x8*)(ap + k0),
                                                      *(const bf16x8*)(bp + k0), acc, 0, 0, 0);
#pragma unroll
      for (int i = 0; i < 4; ++i) {
        const int r = row0 + w * 16 + hi * 4 + i;
        const float v = fmaxf(acc[i] + pbias, 0.0f);
        out[(r * TT + t) * 256 + colp] = v;
        spb[r * 256 + colp] = __float2bfloat16(v);
      }
    }
    grid.sync();
    if (t == 16) break;

    // ---- gates: rows row0+m*16, cols colg, 3 gates ----
    f32x4 aR = {0.f, 0.f, 0.f, 0.f}, aZ = aR, aXN = aR, aHN = aR;
    {
      const __hip_bfloat16* ap = spb + (row0 + m * 16 + l15) * 256 + hi * 8;
      const __hip_bfloat16* bW = wihL + cloc8;
#pragma unroll
      for (int k0 = 0; k0 < 256; k0 += 32) {
        const int kofs = ((k0 >> 3) + hi) * 256;
        bf16x8 a = *(const bf16x8*)(ap + k0);
        aR = __builtin_amdgcn_mfma_f32_16x16x32_bf16(a, *(const bf16x8*)(bW + kofs), aR, 0, 0, 0);
        aZ = __builtin_amdgcn_mfma_f32_16x16x32_bf16(a, *(const bf16x8*)(bW + 8192 + kofs), aZ, 0, 0, 0);
        aXN = __builtin_amdgcn_mfma_f32_16x16x32_bf16(a, *(const bf16x8*)(bW + 16384 + kofs), aXN, 0, 0, 0);
      }
    }
    {
      const __hip_bfloat16* ap = hbc + (row0 + m * 16 + l15) * 512 + hi * 8;
      const __hip_bfloat16* bW = whhL + cloc8;
#pragma unroll
      for (int k0 = 0; k0 < 512; k0 += 32) {
        const int kofs = ((k0 >> 3) + hi) * 256;
        bf16x8 a = *(const bf16x8*)(ap + k0);
        aR = __builtin_amdgcn_mfma_f32_16x16x32_bf16(a, *(const bf16x8*)(bW + kofs), aR, 0, 0, 0);
        aZ = __builtin_amdgcn_mfma_f32_16x16x32_bf16(a, *(const bf16x8*)(bW + 16384 + kofs), aZ, 0, 0, 0);
        aHN = __builtin_amdgcn_mfma_f32_16x16x32_bf16(a, *(const bf16x8*)(bW + 32768 + kofs), aHN, 0, 0, 0);
      }
    }
#pragma unroll
    for (int i = 0; i < 4; ++i) {
      const int r = row0 + m * 16 + hi * 4 + i;  // C/D: row=(lane>>4)*4+reg, col=lane&15
      const float u0 = actions[r * 32 + t * 2 + 0];
      const float u1 = actions[r * 32 + t * 2 + 1];
      const float gr = aR[i] + br + u0 * wur + u1 * wvr;
      const float gz = aZ[i] + bz + u0 * wuz + u1 * wvz;
      const float gxn = aXN[i] + bxn + u0 * wun + u1 * wvn;
      const float ghn = aHN[i] + bhn;
      const float rg = 1.0f / (1.0f + __expf(-gr));
      const float zg = 1.0f / (1.0f + __expf(-gz));
      float xn = gxn + rg * ghn;
      xn = fminf(fmaxf(xn, -15.0f), 15.0f);
      const float e = __expf(2.0f * xn);
      const float ng = (e - 1.0f) / (e + 1.0f);
      const float hp = hc[r * 512 + colg];
      const float hnv = (1.0f - zg) * ng + zg * hp;
      hn_[r * 512 + colg] = hnv;
      hbn[r * 512 + colg] = __float2bfloat16(hnv);
    }
    grid.sync();
  }
}

extern "C" void kernel_launch(void* const* d_in, const int* in_sizes, int n_in,
                              void* d_out, int out_size, void* d_ws, size_t ws_size,
                              hipStream_t stream) {
  const float* x       = (const float*)d_in[0];
  const float* actions = (const float*)d_in[1];
  const float* cw      = (const float*)d_in[2];
  const float* gamma   = (const float*)d_in[3];
  const float* beta    = (const float*)d_in[4];
  const float* fcw     = (const float*)d_in[5];
  const float* fcb     = (const float*)d_in[6];
  const float* wih     = (const float*)d_in[7];
  const float* whh     = (const float*)d_in[8];
  const float* bih     = (const float*)d_in[9];
  const float* bhh     = (const float*)d_in[10];
  const float* pw      = (const float*)d_in[11];
  const float* pb      = (const float*)d_in[12];
  float* out = (float*)d_out;
  float* ws  = (float*)d_ws;

  float* stats  = ws + OFF_STATS;
  float* bstats = ws + OFF_BSTATS;
  float* h0     = ws + OFF_H0;
  float* h1     = ws + OFF_H1;
  __hip_bfloat16* hb0 = (__hip_bfloat16*)(ws + OFF_HB0);
  __hip_bfloat16* hb1 = (__hip_bfloat16*)(ws + OFF_HB1);
  __hip_bfloat16* spb = (__hip_bfloat16*)(ws + OFF_SPB);
  __hip_bfloat16* pwb = (__hip_bfloat16*)(ws + OFF_PWB);

  prep_k<<<dim3(256), dim3(256), 0, stream>>>(pw, pwb, h0, (float*)hb0);
  enc_conv_stats<<<dim3(512), dim3(256), 0, stream>>>(x, cw, bstats);
  reduce_stats_k<<<dim3(1), dim3(256), 0, stream>>>(bstats, stats);
  enc_finish<<<dim3(512), dim3(256), 0, stream>>>(x, cw, stats, gamma, beta, fcw, fcb,
                                                  spb, out);

  void* args[] = {(void*)&spb, (void*)&h0, (void*)&h1, (void*)&hb0, (void*)&hb1,
                  (void*)&wih, (void*)&whh, (void*)&pwb, (void*)&pb, (void*)&actions,
                  (void*)&bih, (void*)&bhh, (void*)&out};
  hipLaunchCooperativeKernel(scan_coop, dim3(256), dim3(256), args,
                             (unsigned int)(73728 * sizeof(__hip_bfloat16)), stream);
}

// Round 6
// 564.867 us; speedup vs baseline: 2.1153x; 2.1153x over previous
//
#include <hip/hip_runtime.h>
#include <hip/hip_bf16.h>
#include <math.h>

#define TM1 16
#define TT 17

typedef __attribute__((ext_vector_type(8))) __bf16 bf16x8;
typedef __attribute__((ext_vector_type(4))) float f32x4;

// ---------------- workspace layout (float units, all 32B-aligned) ----------------
#define OFF_STATS  0          // 32
#define OFF_BSTATS 32         // 512*32
#define OFF_BAR    16416      // 512 ints (16 groups x 32-int lines)
#define OFF_HB0    16928      // 512*512 bf16
#define OFF_HB1    148000     // 512*512 bf16
#define OFF_SPB    279072     // 512*256 bf16
#define OFF_PWB    344608     // 256*512 bf16
#define OFF_WIHP   410144     // 16 x 24576 bf16 (pre-swizzled wih slices)
#define OFF_WHHP   606752     // 16 x 49152 bf16 (pre-swizzled whh slices)
// ends at 999968 floats ~= 4.0 MB

// prep: build bf16 weights (pwb row-major; wih/whh pre-swizzled per col-group into
// [g][kc][c][kl] LDS layout), zero hb0 and barrier counters.
__global__ void prep_k(const float* __restrict__ wih, const float* __restrict__ whh,
                       const float* __restrict__ pw,
                       __hip_bfloat16* __restrict__ pwb,
                       __hip_bfloat16* __restrict__ wihPre,
                       __hip_bfloat16* __restrict__ whhPre,
                       float* __restrict__ hb0f, int* __restrict__ bar) {
  int i = blockIdx.x * blockDim.x + threadIdx.x;
  int st = gridDim.x * blockDim.x;
  for (int j = i; j < 256 * 512; j += st) pwb[j] = __float2bfloat16(pw[j]);
  // wihPre: bx(16) x [g(3)][kc(32)][c(32)][kl(8)]
  for (int j = i; j < 16 * 24576; j += st) {
    int bx = j / 24576, rem = j % 24576;
    int g = rem >> 13, r2 = rem & 8191;
    int kc = r2 >> 8, r3 = r2 & 255, c = r3 >> 3, kl = r3 & 7;
    wihPre[j] = __float2bfloat16(wih[(g * 512 + bx * 32 + c) * 258 + kc * 8 + kl]);
  }
  // whhPre: bx(16) x [g(3)][kc(64)][c(32)][kl(8)]
  for (int j = i; j < 16 * 49152; j += st) {
    int bx = j / 49152, rem = j % 49152;
    int g = rem >> 14, r2 = rem & 16383;
    int kc = r2 >> 8, r3 = r2 & 255, c = r3 >> 3, kl = r3 & 7;
    whhPre[j] = __float2bfloat16(whh[(g * 512 + bx * 32 + c) * 512 + kc * 8 + kl]);
  }
  for (int j = i; j < 512 * 512 / 2; j += st) hb0f[j] = 0.0f;
  for (int j = i; j < 512; j += st) bar[j] = 0;
}

// ---------------- Encoder pass A: conv + per-block channel sum/sumsq ----------------
__global__ __launch_bounds__(256) void enc_conv_stats(const float* __restrict__ x,
                                                      const float* __restrict__ cw,
                                                      float* __restrict__ bstats) {
  __shared__ float imgp[2 * 66 * 66];
  __shared__ float reds[4][16], redq[4][16];
  const int b = blockIdx.x, tid = threadIdx.x;
  const int wv = tid >> 6;
  for (int i = tid; i < 2 * 66 * 66; i += 256) imgp[i] = 0.0f;
  __syncthreads();
  const float* xb = x + b * 8192;
  for (int i = tid; i < 8192; i += 256) {
    int ci = i >> 12, rem = i & 4095, y = rem >> 6, xx = rem & 63;
    imgp[ci * 4356 + (y + 1) * 66 + (xx + 1)] = xb[i];
  }
  __syncthreads();

  for (int c4 = 0; c4 < 4; ++c4) {
    float w0[18], w1[18], w2[18], w3[18];
#pragma unroll
    for (int k = 0; k < 18; ++k) {
      w0[k] = cw[(c4 * 4 + 0) * 18 + k];
      w1[k] = cw[(c4 * 4 + 1) * 18 + k];
      w2[k] = cw[(c4 * 4 + 2) * 18 + k];
      w3[k] = cw[(c4 * 4 + 3) * 18 + k];
    }
    float s0 = 0, s1 = 0, s2 = 0, s3 = 0, q0 = 0, q1 = 0, q2 = 0, q3 = 0;
    for (int p = tid; p < 4096; p += 256) {
      int y = p >> 6, xx = p & 63;
      float v[18];
#pragma unroll
      for (int ci = 0; ci < 2; ++ci)
#pragma unroll
        for (int dy = 0; dy < 3; ++dy)
#pragma unroll
          for (int dx = 0; dx < 3; ++dx)
            v[ci * 9 + dy * 3 + dx] = imgp[ci * 4356 + (y + dy) * 66 + (xx + dx)];
      float a0 = 0, a1 = 0, a2 = 0, a3 = 0;
#pragma unroll
      for (int k = 0; k < 18; ++k) {
        a0 = fmaf(w0[k], v[k], a0);
        a1 = fmaf(w1[k], v[k], a1);
        a2 = fmaf(w2[k], v[k], a2);
        a3 = fmaf(w3[k], v[k], a3);
      }
      s0 += a0; q0 = fmaf(a0, a0, q0);
      s1 += a1; q1 = fmaf(a1, a1, q1);
      s2 += a2; q2 = fmaf(a2, a2, q2);
      s3 += a3; q3 = fmaf(a3, a3, q3);
    }
#pragma unroll
    for (int off = 32; off >= 1; off >>= 1) {
      s0 += __shfl_down(s0, off); q0 += __shfl_down(q0, off);
      s1 += __shfl_down(s1, off); q1 += __shfl_down(q1, off);
      s2 += __shfl_down(s2, off); q2 += __shfl_down(q2, off);
      s3 += __shfl_down(s3, off); q3 += __shfl_down(q3, off);
    }
    if ((tid & 63) == 0) {
      reds[wv][c4 * 4 + 0] = s0; redq[wv][c4 * 4 + 0] = q0;
      reds[wv][c4 * 4 + 1] = s1; redq[wv][c4 * 4 + 1] = q1;
      reds[wv][c4 * 4 + 2] = s2; redq[wv][c4 * 4 + 2] = q2;
      reds[wv][c4 * 4 + 3] = s3; redq[wv][c4 * 4 + 3] = q3;
    }
  }
  __syncthreads();
  if (tid < 16)
    bstats[b * 32 + tid] = reds[0][tid] + reds[1][tid] + reds[2][tid] + reds[3][tid];
  else if (tid < 32) {
    int c = tid - 16;
    bstats[b * 32 + tid] = redq[0][c] + redq[1][c] + redq[2][c] + redq[3][c];
  }
}

// reduce 512 x 32 partials -> 32 stats (deterministic, no atomics)
__global__ __launch_bounds__(256) void reduce_stats_k(const float* __restrict__ bstats,
                                                      float* __restrict__ stats) {
  __shared__ float acc[8][32];
  const int c = threadIdx.x & 31, part = threadIdx.x >> 5;
  float s = 0;
  for (int b = part; b < 512; b += 8) s += bstats[b * 32 + c];
  acc[part][c] = s;
  __syncthreads();
  if (threadIdx.x < 32) {
    float t = 0;
#pragma unroll
    for (int p = 0; p < 8; ++p) t += acc[p][threadIdx.x];
    stats[threadIdx.x] = t;
  }
}

// ---- Encoder pass B: conv + BN + relu + maxpool + avgpool + FC -> s0 ----
__global__ __launch_bounds__(256) void enc_finish(const float* __restrict__ x,
                                                  const float* __restrict__ cw,
                                                  const float* __restrict__ stats,
                                                  const float* __restrict__ gamma,
                                                  const float* __restrict__ beta,
                                                  const float* __restrict__ fcw,
                                                  const float* __restrict__ fcb,
                                                  __hip_bfloat16* __restrict__ spb,
                                                  float* __restrict__ out) {
  __shared__ float imgp[2 * 66 * 66];
  __shared__ float red[4][16];
  __shared__ float plds[16];
  const int b = blockIdx.x, tid = threadIdx.x;
  for (int i = tid; i < 2 * 66 * 66; i += 256) imgp[i] = 0.0f;
  __syncthreads();
  const float* xb = x + b * 8192;
  for (int i = tid; i < 8192; i += 256) {
    int ci = i >> 12, rem = i & 4095, y = rem >> 6, xx = rem & 63;
    imgp[ci * 4356 + (y + 1) * 66 + (xx + 1)] = xb[i];
  }
  __syncthreads();

  const float invN = 1.0f / (512.0f * 4096.0f);
  const int wv = tid >> 6;

  for (int c4 = 0; c4 < 4; ++c4) {
    float w0[18], w1[18], w2[18], w3[18];
#pragma unroll
    for (int k = 0; k < 18; ++k) {
      w0[k] = cw[(c4 * 4 + 0) * 18 + k];
      w1[k] = cw[(c4 * 4 + 1) * 18 + k];
      w2[k] = cw[(c4 * 4 + 2) * 18 + k];
      w3[k] = cw[(c4 * 4 + 3) * 18 + k];
    }
    float sc0, sc1, sc2, sc3, sh0, sh1, sh2, sh3;
    {
      int c = c4 * 4 + 0; float m = stats[c] * invN; float var = stats[16 + c] * invN - m * m;
      float isd = rsqrtf(var + 1e-5f); sc0 = gamma[c] * isd; sh0 = beta[c] - m * sc0;
      c = c4 * 4 + 1; m = stats[c] * invN; var = stats[16 + c] * invN - m * m;
      isd = rsqrtf(var + 1e-5f); sc1 = gamma[c] * isd; sh1 = beta[c] - m * sc1;
      c = c4 * 4 + 2; m = stats[c] * invN; var = stats[16 + c] * invN - m * m;
      isd = rsqrtf(var + 1e-5f); sc2 = gamma[c] * isd; sh2 = beta[c] - m * sc2;
      c = c4 * 4 + 3; m = stats[c] * invN; var = stats[16 + c] * invN - m * m;
      isd = rsqrtf(var + 1e-5f); sc3 = gamma[c] * isd; sh3 = beta[c] - m * sc3;
    }
    float p0 = 0, p1 = 0, p2 = 0, p3 = 0;
    for (int q = tid; q < 1024; q += 256) {
      int py = q >> 5, px = q & 31;
      float m0 = 0, m1 = 0, m2 = 0, m3 = 0;
#pragma unroll
      for (int sy = 0; sy < 2; ++sy)
#pragma unroll
        for (int sx = 0; sx < 2; ++sx) {
          int y = 2 * py + sy, xx = 2 * px + sx;
          float v[18];
#pragma unroll
          for (int ci = 0; ci < 2; ++ci)
#pragma unroll
            for (int dy = 0; dy < 3; ++dy)
#pragma unroll
              for (int dx = 0; dx < 3; ++dx)
                v[ci * 9 + dy * 3 + dx] = imgp[ci * 4356 + (y + dy) * 66 + (xx + dx)];
          float a0 = 0, a1 = 0, a2 = 0, a3 = 0;
#pragma unroll
          for (int k = 0; k < 18; ++k) {
            a0 = fmaf(w0[k], v[k], a0);
            a1 = fmaf(w1[k], v[k], a1);
            a2 = fmaf(w2[k], v[k], a2);
            a3 = fmaf(w3[k], v[k], a3);
          }
          m0 = fmaxf(m0, fmaxf(fmaf(a0, sc0, sh0), 0.0f));
          m1 = fmaxf(m1, fmaxf(fmaf(a1, sc1, sh1), 0.0f));
          m2 = fmaxf(m2, fmaxf(fmaf(a2, sc2, sh2), 0.0f));
          m3 = fmaxf(m3, fmaxf(fmaf(a3, sc3, sh3), 0.0f));
        }
      p0 += m0; p1 += m1; p2 += m2; p3 += m3;
    }
#pragma unroll
    for (int off = 32; off >= 1; off >>= 1) {
      p0 += __shfl_down(p0, off);
      p1 += __shfl_down(p1, off);
      p2 += __shfl_down(p2, off);
      p3 += __shfl_down(p3, off);
    }
    if ((tid & 63) == 0) {
      red[wv][c4 * 4 + 0] = p0;
      red[wv][c4 * 4 + 1] = p1;
      red[wv][c4 * 4 + 2] = p2;
      red[wv][c4 * 4 + 3] = p3;
    }
  }
  __syncthreads();
  if (tid < 16)
    plds[tid] = (red[0][tid] + red[1][tid] + red[2][tid] + red[3][tid]) * (1.0f / 1024.0f);
  __syncthreads();

  float acc = fcb[tid];
#pragma unroll
  for (int c = 0; c < 16; ++c) acc = fmaf(plds[c], fcw[tid * 16 + c], acc);
  spb[b * 256 + tid] = __float2bfloat16(acc);
  out[(b * TT + 0) * 256 + tid] = acc;
}

// ---------------- Persistent scan with per-row-band barriers ----------------
// 256 blocks x 256 thr, 1 block/CU (144 KB LDS). block = (by=row band, bx=col group).
// All cross-block deps live within a row band -> 16-block barriers, not grid-wide.
__global__ __launch_bounds__(256) void scan_coop(
    __hip_bfloat16* __restrict__ spb,
    __hip_bfloat16* __restrict__ hb0, __hip_bfloat16* __restrict__ hb1,
    const __hip_bfloat16* __restrict__ wihPre,
    const __hip_bfloat16* __restrict__ whhPre,
    const __hip_bfloat16* __restrict__ pwb,
    const float* __restrict__ pb,
    const float* __restrict__ actions,
    const float* __restrict__ bih, const float* __restrict__ bhh,
    const float* __restrict__ wih,
    float* __restrict__ out,
    int* __restrict__ bar) {
  __shared__ __hip_bfloat16 whhL[49152];
  __shared__ __hip_bfloat16 wihL[24576];
  const int tid = threadIdx.x;
  const int w = tid >> 6, lane = tid & 63;
  const int l15 = lane & 15, hi = lane >> 4;
  const int bx = blockIdx.x & 15, by = blockIdx.x >> 4;
  const int row0 = by * 32;
  const int m = w & 1, tc = w >> 1;
  int* mybar = bar + by * 32;

  // stage pre-swizzled weight slices (contiguous 16B copies)
  {
    const bf16x8* s1 = (const bf16x8*)(whhPre + (size_t)bx * 49152);
    bf16x8* d1 = (bf16x8*)whhL;
    for (int i = tid; i < 6144; i += 256) d1[i] = s1[i];
    const bf16x8* s2 = (const bf16x8*)(wihPre + (size_t)bx * 24576);
    bf16x8* d2 = (bf16x8*)wihL;
    for (int i = tid; i < 3072; i += 256) d2[i] = s2[i];
  }
  __syncthreads();

  // loop-invariant constants
  const int colg = bx * 32 + tc * 16 + l15;
  const float br = bih[colg] + bhh[colg];
  const float bz = bih[512 + colg] + bhh[512 + colg];
  const float bxn = bih[1024 + colg];
  const float bhn = bhh[1024 + colg];
  const float wur = wih[colg * 258 + 256], wvr = wih[colg * 258 + 257];
  const float wuz = wih[(512 + colg) * 258 + 256], wvz = wih[(512 + colg) * 258 + 257];
  const float wun = wih[(1024 + colg) * 258 + 256], wvn = wih[(1024 + colg) * 258 + 257];
  const int colp = bx * 16 + l15;
  const float pbias = pb[colp];
  const int cloc8 = (tc * 16 + l15) * 8;

  f32x4 hReg = {0.f, 0.f, 0.f, 0.f};  // this thread's fp32 h tile (stationary)
  int phase = 0;

#define GBAR()                                                                        \
  do {                                                                                \
    __syncthreads();                                                                  \
    ++phase;                                                                          \
    if (tid == 0) {                                                                   \
      __hip_atomic_fetch_add(mybar, 1, __ATOMIC_RELEASE, __HIP_MEMORY_SCOPE_AGENT);   \
      while (__hip_atomic_load(mybar, __ATOMIC_ACQUIRE, __HIP_MEMORY_SCOPE_AGENT) <   \
             16 * phase)                                                              \
        __builtin_amdgcn_s_sleep(1);                                                  \
    }                                                                                 \
    __syncthreads();                                                                  \
  } while (0)

  for (int t = 0; t < TM1; ++t) {
    const __hip_bfloat16* hbc = (t & 1) ? hb1 : hb0;
    __hip_bfloat16* hbn = (t & 1) ? hb0 : hb1;

    if (t > 0) {
      if (w < 2) {
        // pred: s(t) = relu(h(t) @ P^T + pb); rows row0+w*16, col colp
        f32x4 acc = {0.f, 0.f, 0.f, 0.f};
        const __hip_bfloat16* ap = hbc + (row0 + w * 16 + l15) * 512 + hi * 8;
        const __hip_bfloat16* bp = pwb + colp * 512 + hi * 8;
#pragma unroll
        for (int k0 = 0; k0 < 512; k0 += 32)
          acc = __builtin_amdgcn_mfma_f32_16x16x32_bf16(
              *(const bf16x8*)(ap + k0), *(const bf16x8*)(bp + k0), acc, 0, 0, 0);
#pragma unroll
        for (int i = 0; i < 4; ++i) {
          const int r = row0 + w * 16 + hi * 4 + i;
          const float v = fmaxf(acc[i] + pbias, 0.0f);
          out[(r * TT + t) * 256 + colp] = v;
          spb[r * 256 + colp] = __float2bfloat16(v);
        }
      }
      GBAR();
    }

    // gates: rows row0+m*16, cols colg
    f32x4 aR = {0.f, 0.f, 0.f, 0.f}, aZ = aR, aXN = aR, aHN = aR;
    {
      const __hip_bfloat16* ap = spb + (row0 + m * 16 + l15) * 256 + hi * 8;
      const __hip_bfloat16* bW = wihL + cloc8;
#pragma unroll
      for (int k0 = 0; k0 < 256; k0 += 32) {
        const int kofs = ((k0 >> 3) + hi) * 256;
        bf16x8 a = *(const bf16x8*)(ap + k0);
        aR = __builtin_amdgcn_mfma_f32_16x16x32_bf16(a, *(const bf16x8*)(bW + kofs), aR, 0, 0, 0);
        aZ = __builtin_amdgcn_mfma_f32_16x16x32_bf16(a, *(const bf16x8*)(bW + 8192 + kofs), aZ, 0, 0, 0);
        aXN = __builtin_amdgcn_mfma_f32_16x16x32_bf16(a, *(const bf16x8*)(bW + 16384 + kofs), aXN, 0, 0, 0);
      }
    }
    {
      const __hip_bfloat16* ap = hbc + (row0 + m * 16 + l15) * 512 + hi * 8;
      const __hip_bfloat16* bW = whhL + cloc8;
#pragma unroll
      for (int k0 = 0; k0 < 512; k0 += 32) {
        const int kofs = ((k0 >> 3) + hi) * 256;
        bf16x8 a = *(const bf16x8*)(ap + k0);
        aR = __builtin_amdgcn_mfma_f32_16x16x32_bf16(a, *(const bf16x8*)(bW + kofs), aR, 0, 0, 0);
        aZ = __builtin_amdgcn_mfma_f32_16x16x32_bf16(a, *(const bf16x8*)(bW + 16384 + kofs), aZ, 0, 0, 0);
        aHN = __builtin_amdgcn_mfma_f32_16x16x32_bf16(a, *(const bf16x8*)(bW + 32768 + kofs), aHN, 0, 0, 0);
      }
    }
#pragma unroll
    for (int i = 0; i < 4; ++i) {
      const int r = row0 + m * 16 + hi * 4 + i;  // C/D: row=(lane>>4)*4+reg, col=lane&15
      const float u0 = actions[r * 32 + t * 2 + 0];
      const float u1 = actions[r * 32 + t * 2 + 1];
      const float gr = aR[i] + br + u0 * wur + u1 * wvr;
      const float gz = aZ[i] + bz + u0 * wuz + u1 * wvz;
      const float gxn = aXN[i] + bxn + u0 * wun + u1 * wvn;
      const float ghn = aHN[i] + bhn;
      const float rg = 1.0f / (1.0f + __expf(-gr));
      const float zg = 1.0f / (1.0f + __expf(-gz));
      float xn = gxn + rg * ghn;
      xn = fminf(fmaxf(xn, -15.0f), 15.0f);
      const float e = __expf(2.0f * xn);
      const float ng = (e - 1.0f) / (e + 1.0f);
      const float hnv = (1.0f - zg) * ng + zg * hReg[i];
      hReg[i] = hnv;
      hbn[r * 512 + colg] = __float2bfloat16(hnv);
    }
    GBAR();
  }

  // final pred: s(16) from h(16) (= hb0 since 16 is even)
  if (w < 2) {
    f32x4 acc = {0.f, 0.f, 0.f, 0.f};
    const __hip_bfloat16* ap = hb0 + (row0 + w * 16 + l15) * 512 + hi * 8;
    const __hip_bfloat16* bp = pwb + colp * 512 + hi * 8;
#pragma unroll
    for (int k0 = 0; k0 < 512; k0 += 32)
      acc = __builtin_amdgcn_mfma_f32_16x16x32_bf16(
          *(const bf16x8*)(ap + k0), *(const bf16x8*)(bp + k0), acc, 0, 0, 0);
#pragma unroll
    for (int i = 0; i < 4; ++i) {
      const int r = row0 + w * 16 + hi * 4 + i;
      const float v = fmaxf(acc[i] + pbias, 0.0f);
      out[(r * TT + 16) * 256 + colp] = v;
    }
  }
#undef GBAR
}

extern "C" void kernel_launch(void* const* d_in, const int* in_sizes, int n_in,
                              void* d_out, int out_size, void* d_ws, size_t ws_size,
                              hipStream_t stream) {
  const float* x       = (const float*)d_in[0];
  const float* actions = (const float*)d_in[1];
  const float* cw      = (const float*)d_in[2];
  const float* gamma   = (const float*)d_in[3];
  const float* beta    = (const float*)d_in[4];
  const float* fcw     = (const float*)d_in[5];
  const float* fcb     = (const float*)d_in[6];
  const float* wih     = (const float*)d_in[7];
  const float* whh     = (const float*)d_in[8];
  const float* bih     = (const float*)d_in[9];
  const float* bhh     = (const float*)d_in[10];
  const float* pw      = (const float*)d_in[11];
  const float* pb      = (const float*)d_in[12];
  float* out = (float*)d_out;
  float* ws  = (float*)d_ws;

  float* stats  = ws + OFF_STATS;
  float* bstats = ws + OFF_BSTATS;
  int*   bar    = (int*)(ws + OFF_BAR);
  __hip_bfloat16* hb0    = (__hip_bfloat16*)(ws + OFF_HB0);
  __hip_bfloat16* hb1    = (__hip_bfloat16*)(ws + OFF_HB1);
  __hip_bfloat16* spb    = (__hip_bfloat16*)(ws + OFF_SPB);
  __hip_bfloat16* pwb    = (__hip_bfloat16*)(ws + OFF_PWB);
  __hip_bfloat16* wihPre = (__hip_bfloat16*)(ws + OFF_WIHP);
  __hip_bfloat16* whhPre = (__hip_bfloat16*)(ws + OFF_WHHP);

  prep_k<<<dim3(512), dim3(256), 0, stream>>>(wih, whh, pw, pwb, wihPre, whhPre,
                                              (float*)hb0, bar);
  enc_conv_stats<<<dim3(512), dim3(256), 0, stream>>>(x, cw, bstats);
  reduce_stats_k<<<dim3(1), dim3(256), 0, stream>>>(bstats, stats);
  enc_finish<<<dim3(512), dim3(256), 0, stream>>>(x, cw, stats, gamma, beta, fcw, fcb,
                                                  spb, out);

  void* args[] = {(void*)&spb, (void*)&hb0, (void*)&hb1, (void*)&wihPre, (void*)&whhPre,
                  (void*)&pwb, (void*)&pb, (void*)&actions, (void*)&bih, (void*)&bhh,
                  (void*)&wih, (void*)&out, (void*)&bar};
  hipLaunchCooperativeKernel(scan_coop, dim3(256), dim3(256), args, 0, stream);
}